// Round 1
// baseline (2213.000 us; speedup 1.0000x reference)
//
#include <hip/hip_runtime.h>
#include <hip/hip_bf16.h>
#include <math.h>

// ---------------------------------------------------------------------------
// Nystrom attention layer, all-f32 correctness-first baseline.
// b=4, n=4096, d=512, h=8, dh=64, m=256 landmarks, l=16, conv K=33.
// out = attn1 @ (pinv(attn2) @ (attn3 @ v))  (re-associated)
// ---------------------------------------------------------------------------

// ---------------- LayerNorm: 16384 rows x 512 ----------------
__global__ __launch_bounds__(256) void ln_kernel(const float* __restrict__ x,
                                                 const float* __restrict__ g,
                                                 const float* __restrict__ b,
                                                 float* __restrict__ xn) {
    int row = blockIdx.x;
    const float* xr = x + (size_t)row * 512;
    int t = threadIdx.x;
    float v0 = xr[t], v1 = xr[t + 256];
    __shared__ float red[4];
    float s = v0 + v1;
#pragma unroll
    for (int off = 32; off; off >>= 1) s += __shfl_down(s, off);
    if ((t & 63) == 0) red[t >> 6] = s;
    __syncthreads();
    float mean = (red[0] + red[1] + red[2] + red[3]) * (1.0f / 512.0f);
    __syncthreads();
    float d0 = v0 - mean, d1 = v1 - mean;
    float q2 = d0 * d0 + d1 * d1;
#pragma unroll
    for (int off = 32; off; off >>= 1) q2 += __shfl_down(q2, off);
    if ((t & 63) == 0) red[t >> 6] = q2;
    __syncthreads();
    float var = (red[0] + red[1] + red[2] + red[3]) * (1.0f / 512.0f);
    float inv = rsqrtf(var + 1e-5f);
    float* o = xn + (size_t)row * 512;
    o[t]       = d0 * inv * g[t]       + b[t];
    o[t + 256] = d1 * inv * g[t + 256] + b[t + 256];
}

// ---------------- QKV GEMM: C[16384,1536] = xn @ w_qkv^T, scatter to q/k/v ----------------
__global__ __launch_bounds__(256) void qkv_gemm(const float* __restrict__ A,
                                                const float* __restrict__ Bw,
                                                float* __restrict__ q,
                                                float* __restrict__ k,
                                                float* __restrict__ v) {
    __shared__ float As[16][132];
    __shared__ float Bs[16][132];
    const int K = 512;
    int t = threadIdx.x;
    int row0 = blockIdx.x * 128, col0 = blockIdx.y * 128;
    int tm = t & 15, tn = t >> 4;
    float acc[8][8];
#pragma unroll
    for (int i = 0; i < 8; ++i)
#pragma unroll
        for (int j = 0; j < 8; ++j) acc[i][j] = 0.f;
    for (int kt = 0; kt < K; kt += 16) {
#pragma unroll
        for (int u = 0; u < 2; ++u) {
            int fid = t + 256 * u;
            int r = fid >> 2, c4 = (fid & 3) << 2;
            float4 av = *(const float4*)(A + (size_t)(row0 + r) * K + kt + c4);
            As[c4 + 0][r] = av.x; As[c4 + 1][r] = av.y; As[c4 + 2][r] = av.z; As[c4 + 3][r] = av.w;
            float4 bv = *(const float4*)(Bw + (size_t)(col0 + r) * K + kt + c4);
            Bs[c4 + 0][r] = bv.x; Bs[c4 + 1][r] = bv.y; Bs[c4 + 2][r] = bv.z; Bs[c4 + 3][r] = bv.w;
        }
        __syncthreads();
#pragma unroll
        for (int kk = 0; kk < 16; ++kk) {
            float a[8], bb[8];
#pragma unroll
            for (int i = 0; i < 8; ++i) a[i] = As[kk][tm * 8 + i];
#pragma unroll
            for (int j = 0; j < 8; ++j) bb[j] = Bs[kk][tn * 8 + j];
#pragma unroll
            for (int i = 0; i < 8; ++i)
#pragma unroll
                for (int j = 0; j < 8; ++j) acc[i][j] = fmaf(a[i], bb[j], acc[i][j]);
        }
        __syncthreads();
    }
#pragma unroll
    for (int i = 0; i < 8; ++i) {
        int grow = row0 + tm * 8 + i;
        int bb2 = grow >> 12, nn = grow & 4095;
#pragma unroll
        for (int j = 0; j < 8; ++j) {
            int gcol = col0 + tn * 8 + j;
            int which = gcol >> 9, rem = gcol & 511;
            int hh = rem >> 6, dd = rem & 63;
            size_t di = (((size_t)(bb2 * 8 + hh)) * 4096 + nn) * 64 + dd;
            float val = acc[i][j];
            if (which == 0) q[di] = val * 0.125f;       // dh^-0.5
            else if (which == 1) k[di] = val;
            else v[di] = val;
        }
    }
}

// ---------------- landmark means (l=16) ----------------
__global__ void landmark_kernel(const float* __restrict__ q, const float* __restrict__ k,
                                float* __restrict__ ql, float* __restrict__ kl) {
    int idx = blockIdx.x * 256 + threadIdx.x;   // 524288
    int dh = idx & 63, mi = (idx >> 6) & 255, bh = idx >> 14;
    size_t base = ((size_t)bh * 4096 + mi * 16) * 64 + dh;
    float sq = 0, sk = 0;
#pragma unroll
    for (int j = 0; j < 16; ++j) { sq += q[base + (size_t)j * 64]; sk += k[base + (size_t)j * 64]; }
    ql[idx] = sq * 0.0625f;
    kl[idx] = sk * 0.0625f;
}

// ---------------- depthwise conv residual -> outh ----------------
__global__ void conv_kernel(const float* __restrict__ v, const float* __restrict__ rw,
                            float* __restrict__ outh) {
    int idx = blockIdx.x * 256 + threadIdx.x;   // 8388608
    int dh = idx & 63, n = (idx >> 6) & 4095, bh = idx >> 18;
    int h = bh & 7;
    const float* vb = v + (((size_t)bh) << 18);
    float s = 0;
#pragma unroll
    for (int tt = 0; tt < 33; ++tt) {
        int j = n + tt - 16;
        if (j >= 0 && j < 4096) s = fmaf(rw[h * 33 + tt], vb[(size_t)j * 64 + dh], s);
    }
    outh[idx] = s;
}

// ---------------- attn2 = softmax(ql @ kl^T) ----------------
__global__ __launch_bounds__(256) void attn2_kernel(const float* __restrict__ ql,
                                                    const float* __restrict__ kl,
                                                    float* __restrict__ a2) {
    int bh = blockIdx.x >> 8, i = blockIdx.x & 255;
    int t = threadIdx.x;
    __shared__ float qrow[64];
    __shared__ float red[4];
    if (t < 64) qrow[t] = ql[((size_t)bh * 256 + i) * 64 + t];
    __syncthreads();
    const float* krow = kl + ((size_t)bh * 256 + t) * 64;
    float s = 0;
#pragma unroll
    for (int c = 0; c < 64; c += 4) {
        float4 kv = *(const float4*)(krow + c);
        s = fmaf(qrow[c], kv.x, s); s = fmaf(qrow[c + 1], kv.y, s);
        s = fmaf(qrow[c + 2], kv.z, s); s = fmaf(qrow[c + 3], kv.w, s);
    }
    float p = __expf(s);    // logits are O(0.1): no max-subtraction needed
    float sum = p;
#pragma unroll
    for (int off = 32; off; off >>= 1) sum += __shfl_down(sum, off);
    if ((t & 63) == 0) red[t >> 6] = sum;
    __syncthreads();
    float tot = red[0] + red[1] + red[2] + red[3];
    a2[((size_t)bh * 256 + i) * 256 + t] = p / tot;
}

// ---------------- max column-sum of attn2 (row-sums are exactly 1) ----------------
__global__ __launch_bounds__(256) void colmax_kernel(const float* __restrict__ a2,
                                                     unsigned* __restrict__ scal) {
    int bh = blockIdx.x, t = threadIdx.x;
    const float* m = a2 + (size_t)bh * 65536;
    float cs = 0;
    for (int i = 0; i < 256; ++i) cs += m[i * 256 + t];
#pragma unroll
    for (int off = 32; off; off >>= 1) cs = fmaxf(cs, __shfl_down(cs, off));
    __shared__ float red[4];
    if ((t & 63) == 0) red[t >> 6] = cs;
    __syncthreads();
    if (t == 0) {
        float mx = fmaxf(fmaxf(red[0], red[1]), fmaxf(red[2], red[3]));
        atomicMax(scal, __float_as_uint(mx));   // nonneg floats: uint order == float order
    }
}

// ---------------- z0 = attn2^T / (1 * colsum_max), tiled transpose ----------------
__global__ __launch_bounds__(256) void z0_kernel(const float* __restrict__ a2,
                                                 const float* __restrict__ scal,
                                                 float* __restrict__ z) {
    int bh = blockIdx.z;
    int ib = blockIdx.x * 64, jb = blockIdx.y * 64;
    __shared__ float tl[64][65];
    float c = 1.0f / *scal;
    int t = threadIdx.x;
#pragma unroll
    for (int u = 0; u < 16; ++u) {
        int idx = t + 256 * u;
        int r = idx >> 6, cc = idx & 63;
        tl[r][cc] = a2[(size_t)bh * 65536 + (size_t)(jb + r) * 256 + ib + cc];
    }
    __syncthreads();
#pragma unroll
    for (int u = 0; u < 16; ++u) {
        int idx = t + 256 * u;
        int r = idx >> 6, cc = idx & 63;
        z[(size_t)bh * 65536 + (size_t)(ib + r) * 256 + jb + cc] = tl[cc][r] * c;
    }
}

// ---------------- batched GEMM: D = alpha*(A@B) + gamma*E  (per batch s) ----------------
__global__ __launch_bounds__(256) void bgemm_kernel(const float* __restrict__ A,
                                                    const float* __restrict__ B,
                                                    float* __restrict__ D,
                                                    const float* __restrict__ E,
                                                    int M, int N, int K,
                                                    float alpha, float gamma) {
    int s = blockIdx.z;
    int bm = blockIdx.x, bn = blockIdx.y;
    A += (size_t)s * M * K; B += (size_t)s * K * N; D += (size_t)s * M * N;
    const float* Ep = E ? E + (size_t)s * M * N : nullptr;
    __shared__ float As[32][67];
    __shared__ float Bs[32][68];
    int t = threadIdx.x;
    int tm = t & 15, tn = t >> 4;
    float acc[4][4];
#pragma unroll
    for (int i = 0; i < 4; ++i)
#pragma unroll
        for (int j = 0; j < 4; ++j) acc[i][j] = 0.f;
    for (int kt = 0; kt < K; kt += 32) {
#pragma unroll
        for (int u = 0; u < 2; ++u) {
            int fid = t + 256 * u;
            int r = fid >> 3, kg = (fid & 7) << 2;
            float4 av = *(const float4*)(A + (size_t)(bm * 64 + r) * K + kt + kg);
            As[kg + 0][r] = av.x; As[kg + 1][r] = av.y; As[kg + 2][r] = av.z; As[kg + 3][r] = av.w;
            int kr = fid >> 4, cg = (fid & 15) << 2;
            float4 bv = *(const float4*)(B + (size_t)(kt + kr) * N + bn * 64 + cg);
            *(float4*)(&Bs[kr][cg]) = bv;
        }
        __syncthreads();
#pragma unroll
        for (int kk = 0; kk < 32; ++kk) {
            float a[4], bb[4];
#pragma unroll
            for (int i = 0; i < 4; ++i) a[i] = As[kk][tm * 4 + i];
#pragma unroll
            for (int j = 0; j < 4; ++j) bb[j] = Bs[kk][tn * 4 + j];
#pragma unroll
            for (int i = 0; i < 4; ++i)
#pragma unroll
                for (int j = 0; j < 4; ++j) acc[i][j] = fmaf(a[i], bb[j], acc[i][j]);
        }
        __syncthreads();
    }
#pragma unroll
    for (int i = 0; i < 4; ++i) {
        int r = bm * 64 + tm * 4 + i;
#pragma unroll
        for (int j = 0; j < 4; ++j) {
            int c = bn * 64 + tn * 4 + j;
            float val = alpha * acc[i][j];
            if (Ep) val = fmaf(gamma, Ep[(size_t)r * N + c], val);
            D[(size_t)r * N + c] = val;
        }
    }
}

// ---------------- attn3@v fused softmax (j-split partials) ----------------
__global__ __launch_bounds__(256) void attn3v_kernel(const float* __restrict__ ql,
                                                     const float* __restrict__ kg,
                                                     const float* __restrict__ vg,
                                                     float* __restrict__ num_part,
                                                     float* __restrict__ den_part) {
    int it = blockIdx.x;   // 4 tiles of 64 landmark rows
    int js = blockIdx.y;   // 4 splits of j (1024 each)
    int bh = blockIdx.z;
    __shared__ float qs[64][65];
    __shared__ float ks[32][65];
    __shared__ float vs[32][64];
    __shared__ float sl[64][33];
    __shared__ float den[64];
    int t = threadIdx.x;
    int i0 = it * 64;
#pragma unroll
    for (int u = 0; u < 4; ++u) {
        int fid = t + 256 * u;
        int r = fid >> 4, c4 = (fid & 15) << 2;
        float4 qv = *(const float4*)(ql + ((size_t)bh * 256 + i0 + r) * 64 + c4);
        qs[r][c4 + 0] = qv.x; qs[r][c4 + 1] = qv.y; qs[r][c4 + 2] = qv.z; qs[r][c4 + 3] = qv.w;
    }
    if (t < 64) den[t] = 0.f;
    float acc[16];
#pragma unroll
    for (int r = 0; r < 16; ++r) acc[r] = 0.f;
    int ti = t & 15, tj = t >> 4;
    int ii = t >> 6, dh = t & 63;
    __syncthreads();
    for (int ch = 0; ch < 32; ++ch) {
        int j0 = js * 1024 + ch * 32;
#pragma unroll
        for (int u = 0; u < 2; ++u) {
            int fid = t + 256 * u;
            int r = fid >> 4, c4 = (fid & 15) << 2;
            size_t gi = ((size_t)bh * 4096 + j0 + r) * 64 + c4;
            float4 kv = *(const float4*)(kg + gi);
            ks[r][c4 + 0] = kv.x; ks[r][c4 + 1] = kv.y; ks[r][c4 + 2] = kv.z; ks[r][c4 + 3] = kv.w;
            *(float4*)(&vs[r][c4]) = *(const float4*)(vg + gi);
        }
        __syncthreads();
        float s00 = 0, s01 = 0, s10 = 0, s11 = 0, s20 = 0, s21 = 0, s30 = 0, s31 = 0;
#pragma unroll 8
        for (int c = 0; c < 64; ++c) {
            float b0 = ks[tj * 2 + 0][c], b1 = ks[tj * 2 + 1][c];
            float a0 = qs[ti * 4 + 0][c]; s00 = fmaf(a0, b0, s00); s01 = fmaf(a0, b1, s01);
            float a1 = qs[ti * 4 + 1][c]; s10 = fmaf(a1, b0, s10); s11 = fmaf(a1, b1, s11);
            float a2 = qs[ti * 4 + 2][c]; s20 = fmaf(a2, b0, s20); s21 = fmaf(a2, b1, s21);
            float a3 = qs[ti * 4 + 3][c]; s30 = fmaf(a3, b0, s30); s31 = fmaf(a3, b1, s31);
        }
        sl[ti * 4 + 0][tj * 2 + 0] = __expf(s00); sl[ti * 4 + 0][tj * 2 + 1] = __expf(s01);
        sl[ti * 4 + 1][tj * 2 + 0] = __expf(s10); sl[ti * 4 + 1][tj * 2 + 1] = __expf(s11);
        sl[ti * 4 + 2][tj * 2 + 0] = __expf(s20); sl[ti * 4 + 2][tj * 2 + 1] = __expf(s21);
        sl[ti * 4 + 3][tj * 2 + 0] = __expf(s30); sl[ti * 4 + 3][tj * 2 + 1] = __expf(s31);
        __syncthreads();
        if (t < 64) {
            float ds = 0;
#pragma unroll
            for (int jl = 0; jl < 32; ++jl) ds += sl[t][jl];
            den[t] += ds;
        }
#pragma unroll
        for (int r = 0; r < 16; ++r) {
            int i = ii * 16 + r;
            float pa = 0;
#pragma unroll
            for (int jl = 0; jl < 32; ++jl) pa = fmaf(sl[i][jl], vs[jl][dh], pa);
            acc[r] += pa;
        }
        __syncthreads();
    }
#pragma unroll
    for (int r = 0; r < 16; ++r) {
        int i = ii * 16 + r;
        num_part[(((size_t)js * 32 + bh) * 256 + i0 + i) * 64 + dh] = acc[r];
    }
    if (t < 64) den_part[((size_t)js * 32 + bh) * 256 + i0 + t] = den[t];
}

// ---------------- combine attn3v partials ----------------
__global__ void a3v_combine(const float* __restrict__ num_part,
                            const float* __restrict__ den_part,
                            float* __restrict__ a3v) {
    int idx = blockIdx.x * 256 + threadIdx.x;  // 524288
    int dh = idx & 63;
    int rest = idx >> 6;
    float n = 0, d = 0;
#pragma unroll
    for (int s = 0; s < 4; ++s) {
        n += num_part[((size_t)s * 8192 + rest) * 64 + dh];
        d += den_part[(size_t)s * 8192 + rest];
    }
    a3v[idx] = n / d;
}

// ---------------- attn1 fused softmax @ w2, += into outh ----------------
__global__ __launch_bounds__(256) void attn1_kernel(const float* __restrict__ q,
                                                    const float* __restrict__ klm,
                                                    const float* __restrict__ w2,
                                                    float* __restrict__ outh) {
    int i0 = blockIdx.x * 64;    // 64 tiles over n=4096
    int bh = blockIdx.y;
    __shared__ float qs[64][65];
    __shared__ float ks[32][65];
    __shared__ float vs[32][64];
    __shared__ float sl[64][33];
    __shared__ float den[64];
    int t = threadIdx.x;
#pragma unroll
    for (int u = 0; u < 4; ++u) {
        int fid = t + 256 * u;
        int r = fid >> 4, c4 = (fid & 15) << 2;
        float4 qv = *(const float4*)(q + ((size_t)bh * 4096 + i0 + r) * 64 + c4);
        qs[r][c4 + 0] = qv.x; qs[r][c4 + 1] = qv.y; qs[r][c4 + 2] = qv.z; qs[r][c4 + 3] = qv.w;
    }
    if (t < 64) den[t] = 0.f;
    float acc[16];
#pragma unroll
    for (int r = 0; r < 16; ++r) acc[r] = 0.f;
    int ti = t & 15, tj = t >> 4;
    int ii = t >> 6, dh = t & 63;
    __syncthreads();
    for (int ch = 0; ch < 8; ++ch) {
        int j0 = ch * 32;
#pragma unroll
        for (int u = 0; u < 2; ++u) {
            int fid = t + 256 * u;
            int r = fid >> 4, c4 = (fid & 15) << 2;
            size_t gi = ((size_t)bh * 256 + j0 + r) * 64 + c4;
            float4 kv = *(const float4*)(klm + gi);
            ks[r][c4 + 0] = kv.x; ks[r][c4 + 1] = kv.y; ks[r][c4 + 2] = kv.z; ks[r][c4 + 3] = kv.w;
            *(float4*)(&vs[r][c4]) = *(const float4*)(w2 + gi);
        }
        __syncthreads();
        float s00 = 0, s01 = 0, s10 = 0, s11 = 0, s20 = 0, s21 = 0, s30 = 0, s31 = 0;
#pragma unroll 8
        for (int c = 0; c < 64; ++c) {
            float b0 = ks[tj * 2 + 0][c], b1 = ks[tj * 2 + 1][c];
            float a0 = qs[ti * 4 + 0][c]; s00 = fmaf(a0, b0, s00); s01 = fmaf(a0, b1, s01);
            float a1 = qs[ti * 4 + 1][c]; s10 = fmaf(a1, b0, s10); s11 = fmaf(a1, b1, s11);
            float a2 = qs[ti * 4 + 2][c]; s20 = fmaf(a2, b0, s20); s21 = fmaf(a2, b1, s21);
            float a3 = qs[ti * 4 + 3][c]; s30 = fmaf(a3, b0, s30); s31 = fmaf(a3, b1, s31);
        }
        sl[ti * 4 + 0][tj * 2 + 0] = __expf(s00); sl[ti * 4 + 0][tj * 2 + 1] = __expf(s01);
        sl[ti * 4 + 1][tj * 2 + 0] = __expf(s10); sl[ti * 4 + 1][tj * 2 + 1] = __expf(s11);
        sl[ti * 4 + 2][tj * 2 + 0] = __expf(s20); sl[ti * 4 + 2][tj * 2 + 1] = __expf(s21);
        sl[ti * 4 + 3][tj * 2 + 0] = __expf(s30); sl[ti * 4 + 3][tj * 2 + 1] = __expf(s31);
        __syncthreads();
        if (t < 64) {
            float ds = 0;
#pragma unroll
            for (int jl = 0; jl < 32; ++jl) ds += sl[t][jl];
            den[t] += ds;
        }
#pragma unroll
        for (int r = 0; r < 16; ++r) {
            int i = ii * 16 + r;
            float pa = 0;
#pragma unroll
            for (int jl = 0; jl < 32; ++jl) pa = fmaf(sl[i][jl], vs[jl][dh], pa);
            acc[r] += pa;
        }
        __syncthreads();
    }
#pragma unroll
    for (int r = 0; r < 16; ++r) {
        int i = ii * 16 + r;
        size_t oi = ((size_t)bh * 4096 + i0 + i) * 64 + dh;
        outh[oi] += acc[r] / den[i];
    }
}

// ---------------- out projection: gather heads, @ w_out^T + b_out + x ----------------
__global__ __launch_bounds__(256) void proj_gemm(const float* __restrict__ outh,
                                                 const float* __restrict__ Bw,
                                                 const float* __restrict__ bias,
                                                 const float* __restrict__ xres,
                                                 float* __restrict__ out) {
    __shared__ float As[16][132];
    __shared__ float Bs[16][132];
    const int K = 512;
    int t = threadIdx.x;
    int row0 = blockIdx.x * 128, col0 = blockIdx.y * 128;
    int tm = t & 15, tn = t >> 4;
    float acc[8][8];
#pragma unroll
    for (int i = 0; i < 8; ++i)
#pragma unroll
        for (int j = 0; j < 8; ++j) acc[i][j] = 0.f;
    for (int kt = 0; kt < K; kt += 16) {
#pragma unroll
        for (int u = 0; u < 2; ++u) {
            int fid = t + 256 * u;
            int r = fid >> 2, c4 = (fid & 3) << 2;
            int grow = row0 + r;
            int bb2 = grow >> 12, nn = grow & 4095;
            int kc = kt + c4;
            int hh = kc >> 6, dd = kc & 63;
            float4 av = *(const float4*)(outh + (((size_t)(bb2 * 8 + hh)) * 4096 + nn) * 64 + dd);
            As[c4 + 0][r] = av.x; As[c4 + 1][r] = av.y; As[c4 + 2][r] = av.z; As[c4 + 3][r] = av.w;
            float4 bv = *(const float4*)(Bw + (size_t)(col0 + r) * K + kt + c4);
            Bs[c4 + 0][r] = bv.x; Bs[c4 + 1][r] = bv.y; Bs[c4 + 2][r] = bv.z; Bs[c4 + 3][r] = bv.w;
        }
        __syncthreads();
#pragma unroll
        for (int kk = 0; kk < 16; ++kk) {
            float a[8], bb[8];
#pragma unroll
            for (int i = 0; i < 8; ++i) a[i] = As[kk][tm * 8 + i];
#pragma unroll
            for (int j = 0; j < 8; ++j) bb[j] = Bs[kk][tn * 8 + j];
#pragma unroll
            for (int i = 0; i < 8; ++i)
#pragma unroll
                for (int j = 0; j < 8; ++j) acc[i][j] = fmaf(a[i], bb[j], acc[i][j]);
        }
        __syncthreads();
    }
#pragma unroll
    for (int i = 0; i < 8; ++i) {
        int grow = row0 + tm * 8 + i;
        const float* xr = xres + (size_t)grow * 512;
        float* orow = out + (size_t)grow * 512;
#pragma unroll
        for (int j = 0; j < 8; ++j) {
            int gcol = col0 + tn * 8 + j;
            orow[gcol] = acc[i][j] + bias[gcol] + xr[gcol];
        }
    }
}

// ---------------------------------------------------------------------------
extern "C" void kernel_launch(void* const* d_in, const int* in_sizes, int n_in,
                              void* d_out, int out_size, void* d_ws, size_t ws_size,
                              hipStream_t stream) {
    (void)in_sizes; (void)n_in; (void)out_size; (void)ws_size;
    const float* x     = (const float*)d_in[0];
    const float* ln_g  = (const float*)d_in[1];
    const float* ln_b  = (const float*)d_in[2];
    const float* w_qkv = (const float*)d_in[3];
    const float* w_out = (const float*)d_in[4];
    const float* b_out = (const float*)d_in[5];
    const float* res_w = (const float*)d_in[6];
    float* out = (float*)d_out;

    float* ws = (float*)d_ws;
    float* xn   = ws;
    float* q    = ws + 8388608;
    float* kk   = ws + 16777216;
    float* vv   = ws + 25165824;
    float* outh = ws + 33554432;
    float* ql   = ws + 41943040;
    float* kl   = ws + 42467328;
    float* a2   = ws + 42991616;
    float* z0   = ws + 45088768;
    float* z1   = ws + 47185920;
    float* xz   = ws + 49283072;
    float* t1   = ws + 51380224;
    float* t2   = ws + 53477376;
    unsigned* scal = (unsigned*)(ws + 55574528);
    // aliases into xn (dead after qkv_gemm)
    float* num_part = xn;                   // 2097152
    float* den_part = xn + 2097152;         // 32768
    float* a3v      = xn + 2129920;         // 524288
    float* w2       = xn + 2654208;         // 524288

    hipMemsetAsync(scal, 0, 4, stream);
    ln_kernel<<<16384, 256, 0, stream>>>(x, ln_g, ln_b, xn);
    qkv_gemm<<<dim3(128, 12), 256, 0, stream>>>(xn, w_qkv, q, kk, vv);
    landmark_kernel<<<2048, 256, 0, stream>>>(q, kk, ql, kl);
    conv_kernel<<<32768, 256, 0, stream>>>(vv, res_w, outh);
    attn2_kernel<<<8192, 256, 0, stream>>>(ql, kl, a2);
    colmax_kernel<<<32, 256, 0, stream>>>(a2, scal);
    z0_kernel<<<dim3(4, 4, 32), 256, 0, stream>>>(a2, (const float*)scal, z0);
    float* zc = z0; float* za = z1;
    for (int itr = 0; itr < 6; ++itr) {
        bgemm_kernel<<<dim3(4, 4, 32), 256, 0, stream>>>(a2, zc, xz, nullptr, 256, 256, 256, 1.f, 0.f);
        bgemm_kernel<<<dim3(4, 4, 32), 256, 0, stream>>>(xz, xz, t1, xz, 256, 256, 256, -1.f, 7.f);
        bgemm_kernel<<<dim3(4, 4, 32), 256, 0, stream>>>(xz, t1, t2, xz, 256, 256, 256, -1.f, 15.f);
        bgemm_kernel<<<dim3(4, 4, 32), 256, 0, stream>>>(zc, t2, za, zc, 256, 256, 256, -0.25f, 3.25f);
        float* tmp = zc; zc = za; za = tmp;
    }
    attn3v_kernel<<<dim3(4, 4, 32), 256, 0, stream>>>(ql, kk, vv, num_part, den_part);
    a3v_combine<<<2048, 256, 0, stream>>>(num_part, den_part, a3v);
    bgemm_kernel<<<dim3(4, 1, 32), 256, 0, stream>>>(zc, a3v, w2, nullptr, 256, 64, 256, 1.f, 0.f);
    attn1_kernel<<<dim3(64, 32), 256, 0, stream>>>(q, kl, w2, outh);
    proj_gemm<<<dim3(128, 4), 256, 0, stream>>>(outh, w_out, b_out, x, out);
}

// Round 3
// 1400.854 us; speedup vs baseline: 1.5798x; 1.5798x over previous
//
#include <hip/hip_runtime.h>
#include <hip/hip_bf16.h>
#include <math.h>

// ---------------------------------------------------------------------------
// Nystrom attention layer. Round 2 (resubmit after infra timeout): bf16 MFMA
// for all forward GEMMs (qkv, attn3v, attn1, proj); pinv Newton-Schulz f32.
// b=4, n=4096, d=512, h=8, dh=64, m=256 landmarks, l=16, conv K=33.
// out = attn1 @ (pinv(attn2) @ (attn3 @ v))  (re-associated)
// ---------------------------------------------------------------------------

using bf16x8 = __attribute__((ext_vector_type(8))) short;
using f32x4  = __attribute__((ext_vector_type(4))) float;

static __device__ __forceinline__ f32x4 MFMA16(bf16x8 a, bf16x8 b, f32x4 c) {
    return __builtin_amdgcn_mfma_f32_16x16x32_bf16(a, b, c, 0, 0, 0);
}
static __device__ __forceinline__ unsigned short f2b(float f) {
    union { float f; unsigned u; } x; x.f = f;
    unsigned r = x.u + 0x7FFFu + ((x.u >> 16) & 1u);
    return (unsigned short)(r >> 16);
}
static __device__ __forceinline__ float b2f(unsigned short b) {
    union { unsigned u; float f; } x; x.u = ((unsigned)b) << 16; return x.f;
}

// ---------------- LayerNorm: 16384 rows x 512, bf16 out ----------------
__global__ __launch_bounds__(256) void ln_kernel(const float* __restrict__ x,
                                                 const float* __restrict__ g,
                                                 const float* __restrict__ b,
                                                 unsigned short* __restrict__ xn) {
    int row = blockIdx.x;
    const float* xr = x + (size_t)row * 512;
    int t = threadIdx.x;
    float v0 = xr[t], v1 = xr[t + 256];
    __shared__ float red[4];
    float s = v0 + v1;
#pragma unroll
    for (int off = 32; off; off >>= 1) s += __shfl_down(s, off);
    if ((t & 63) == 0) red[t >> 6] = s;
    __syncthreads();
    float mean = (red[0] + red[1] + red[2] + red[3]) * (1.0f / 512.0f);
    __syncthreads();
    float d0 = v0 - mean, d1 = v1 - mean;
    float q2 = d0 * d0 + d1 * d1;
#pragma unroll
    for (int off = 32; off; off >>= 1) q2 += __shfl_down(q2, off);
    if ((t & 63) == 0) red[t >> 6] = q2;
    __syncthreads();
    float var = (red[0] + red[1] + red[2] + red[3]) * (1.0f / 512.0f);
    float inv = rsqrtf(var + 1e-5f);
    unsigned short* o = xn + (size_t)row * 512;
    o[t]       = f2b(d0 * inv * g[t]       + b[t]);
    o[t + 256] = f2b(d1 * inv * g[t + 256] + b[t + 256]);
}

// ---------------- weight conversion f32 -> bf16 ----------------
__global__ void cvt_kernel(const float* __restrict__ wqkv, const float* __restrict__ wout,
                           unsigned short* __restrict__ wqkvb, unsigned short* __restrict__ woutb) {
    int idx = blockIdx.x * 256 + threadIdx.x;   // 1048576
    if (idx < 786432) wqkvb[idx] = f2b(wqkv[idx]);
    else woutb[idx - 786432] = f2b(wout[idx - 786432]);
}

// ---------------- bf16 MFMA GEMM: C[M,*] = A[M,512] @ Bw[N,512]^T ----------------
// MODE 0: qkv (scatter q*0.125 / k / v bf16, [bh][n][dh])
// MODE 1: proj (out = acc + bias + x residual, f32 [16384][512])
template<int MODE>
__global__ __launch_bounds__(256) void gemm_mfma(const unsigned short* __restrict__ A,
                                                 const unsigned short* __restrict__ Bw,
                                                 unsigned short* __restrict__ qb,
                                                 unsigned short* __restrict__ kb,
                                                 unsigned short* __restrict__ vb,
                                                 const float* __restrict__ bias,
                                                 const float* __restrict__ xres,
                                                 float* __restrict__ out) {
    const int K = 512;
    __shared__ unsigned short As[128][40];
    __shared__ unsigned short Bs[128][40];
    int t = threadIdx.x;
    int w = t >> 6, l = t & 63, lr = l & 15, g = l >> 4;
    int wm = w >> 1, wn = w & 1;
    int row0 = blockIdx.x * 128, col0 = blockIdx.y * 128;
    f32x4 acc[4][4];
#pragma unroll
    for (int i = 0; i < 4; ++i)
#pragma unroll
        for (int j = 0; j < 4; ++j) acc[i][j] = (f32x4)0.f;
    int srow = t >> 1, sh = t & 1;
    for (int kt = 0; kt < K; kt += 32) {
        const unsigned short* as = A + (size_t)(row0 + srow) * K + kt + sh * 16;
        *(uint4*)&As[srow][sh * 16]     = *(const uint4*)as;
        *(uint4*)&As[srow][sh * 16 + 8] = *(const uint4*)(as + 8);
        const unsigned short* bs = Bw + (size_t)(col0 + srow) * K + kt + sh * 16;
        *(uint4*)&Bs[srow][sh * 16]     = *(const uint4*)bs;
        *(uint4*)&Bs[srow][sh * 16 + 8] = *(const uint4*)(bs + 8);
        __syncthreads();
        bf16x8 a[4], b[4];
#pragma unroll
        for (int mt = 0; mt < 4; ++mt) a[mt] = *(const bf16x8*)&As[wm * 64 + mt * 16 + lr][g * 8];
#pragma unroll
        for (int nt = 0; nt < 4; ++nt) b[nt] = *(const bf16x8*)&Bs[wn * 64 + nt * 16 + lr][g * 8];
#pragma unroll
        for (int mt = 0; mt < 4; ++mt)
#pragma unroll
            for (int nt = 0; nt < 4; ++nt) acc[mt][nt] = MFMA16(a[mt], b[nt], acc[mt][nt]);
        __syncthreads();
    }
#pragma unroll
    for (int mt = 0; mt < 4; ++mt) {
#pragma unroll
        for (int nt = 0; nt < 4; ++nt) {
#pragma unroll
            for (int r = 0; r < 4; ++r) {
                int row = row0 + wm * 64 + mt * 16 + g * 4 + r;
                int col = col0 + wn * 64 + nt * 16 + lr;
                float val = acc[mt][nt][r];
                if (MODE == 0) {
                    int bb = row >> 12, nn = row & 4095;
                    int which = col >> 9, rem = col & 511;
                    int hh = rem >> 6, dd = rem & 63;
                    size_t di = (((size_t)(bb * 8 + hh)) * 4096 + nn) * 64 + dd;
                    if (which == 0) qb[di] = f2b(val * 0.125f);
                    else if (which == 1) kb[di] = f2b(val);
                    else vb[di] = f2b(val);
                } else {
                    out[(size_t)row * 512 + col] = val + bias[col] + xres[(size_t)row * 512 + col];
                }
            }
        }
    }
}

// ---------------- transpose v_bf -> vt_bf [bh][dh][n] ----------------
__global__ __launch_bounds__(256) void vt_kernel(const unsigned short* __restrict__ vb,
                                                 unsigned short* __restrict__ vtb) {
    int n0 = blockIdx.x * 64, bh = blockIdx.y;
    __shared__ unsigned short tl[64][72];
    int t = threadIdx.x;
#pragma unroll
    for (int u = 0; u < 2; ++u) {
        int cid = t * 2 + u;
        int r = cid >> 3, c8 = (cid & 7) << 3;
        uint4 vv = *(const uint4*)(vb + ((size_t)bh * 4096 + n0 + r) * 64 + c8);
        unsigned short* pv = (unsigned short*)&vv;
#pragma unroll
        for (int i = 0; i < 8; ++i) tl[c8 + i][r] = pv[i];
    }
    __syncthreads();
#pragma unroll
    for (int u = 0; u < 2; ++u) {
        int cid = t * 2 + u;
        int r = cid >> 3, c8 = (cid & 7) << 3;
        *(uint4*)(vtb + ((size_t)bh * 64 + r) * 4096 + n0 + c8) = *(uint4*)&tl[r][c8];
    }
}

// ---------------- landmark means (l=16), f32 + bf16 outs ----------------
__global__ void landmark_kernel(const unsigned short* __restrict__ q,
                                const unsigned short* __restrict__ k,
                                float* __restrict__ ql, float* __restrict__ kl,
                                unsigned short* __restrict__ qlb, unsigned short* __restrict__ klb) {
    int idx = blockIdx.x * 256 + threadIdx.x;   // 524288
    int dh = idx & 63, mi = (idx >> 6) & 255, bh = idx >> 14;
    size_t base = ((size_t)bh * 4096 + mi * 16) * 64 + dh;
    float sq = 0, sk = 0;
#pragma unroll
    for (int j = 0; j < 16; ++j) { sq += b2f(q[base + (size_t)j * 64]); sk += b2f(k[base + (size_t)j * 64]); }
    sq *= 0.0625f; sk *= 0.0625f;
    ql[idx] = sq; kl[idx] = sk;
    qlb[idx] = f2b(sq); klb[idx] = f2b(sk);
}

// ---------------- depthwise conv residual -> outh (f32 [bh][n][dh]) ----------------
__global__ void conv_kernel(const unsigned short* __restrict__ v, const float* __restrict__ rw,
                            float* __restrict__ outh) {
    int idx = blockIdx.x * 256 + threadIdx.x;   // 8388608
    int dh = idx & 63, n = (idx >> 6) & 4095, bh = idx >> 18;
    int h = bh & 7;
    const unsigned short* vbp = v + (((size_t)bh) << 18);
    float s = 0;
#pragma unroll
    for (int tt = 0; tt < 33; ++tt) {
        int j = n + tt - 16;
        if (j >= 0 && j < 4096) s = fmaf(rw[h * 33 + tt], b2f(vbp[(size_t)j * 64 + dh]), s);
    }
    outh[idx] = s;
}

// ---------------- attn2 = softmax(ql @ kl^T), f32 ----------------
__global__ __launch_bounds__(256) void attn2_kernel(const float* __restrict__ ql,
                                                    const float* __restrict__ kl,
                                                    float* __restrict__ a2) {
    int bh = blockIdx.x >> 8, i = blockIdx.x & 255;
    int t = threadIdx.x;
    __shared__ float qrow[64];
    __shared__ float red[4];
    if (t < 64) qrow[t] = ql[((size_t)bh * 256 + i) * 64 + t];
    __syncthreads();
    const float* krow = kl + ((size_t)bh * 256 + t) * 64;
    float s = 0;
#pragma unroll
    for (int c = 0; c < 64; c += 4) {
        float4 kv = *(const float4*)(krow + c);
        s = fmaf(qrow[c], kv.x, s); s = fmaf(qrow[c + 1], kv.y, s);
        s = fmaf(qrow[c + 2], kv.z, s); s = fmaf(qrow[c + 3], kv.w, s);
    }
    float p = __expf(s);    // logits are O(0.05): no max-subtraction needed
    float sum = p;
#pragma unroll
    for (int off = 32; off; off >>= 1) sum += __shfl_down(sum, off);
    if ((t & 63) == 0) red[t >> 6] = sum;
    __syncthreads();
    float tot = red[0] + red[1] + red[2] + red[3];
    a2[((size_t)bh * 256 + i) * 256 + t] = p / tot;
}

// ---------------- max column-sum of attn2 (row-sums are exactly 1) ----------------
__global__ __launch_bounds__(256) void colmax_kernel(const float* __restrict__ a2,
                                                     unsigned* __restrict__ scal) {
    int bh = blockIdx.x, t = threadIdx.x;
    const float* m = a2 + (size_t)bh * 65536;
    float cs = 0;
    for (int i = 0; i < 256; ++i) cs += m[i * 256 + t];
#pragma unroll
    for (int off = 32; off; off >>= 1) cs = fmaxf(cs, __shfl_down(cs, off));
    __shared__ float red[4];
    if ((t & 63) == 0) red[t >> 6] = cs;
    __syncthreads();
    if (t == 0) {
        float mx = fmaxf(fmaxf(red[0], red[1]), fmaxf(red[2], red[3]));
        atomicMax(scal, __float_as_uint(mx));
    }
}

// ---------------- z0 = attn2^T / colsum_max ----------------
__global__ __launch_bounds__(256) void z0_kernel(const float* __restrict__ a2,
                                                 const float* __restrict__ scal,
                                                 float* __restrict__ z) {
    int bh = blockIdx.z;
    int ib = blockIdx.x * 64, jb = blockIdx.y * 64;
    __shared__ float tl[64][65];
    float c = 1.0f / *scal;
    int t = threadIdx.x;
#pragma unroll
    for (int u = 0; u < 16; ++u) {
        int idx = t + 256 * u;
        int r = idx >> 6, cc = idx & 63;
        tl[r][cc] = a2[(size_t)bh * 65536 + (size_t)(jb + r) * 256 + ib + cc];
    }
    __syncthreads();
#pragma unroll
    for (int u = 0; u < 16; ++u) {
        int idx = t + 256 * u;
        int r = idx >> 6, cc = idx & 63;
        z[(size_t)bh * 65536 + (size_t)(ib + r) * 256 + jb + cc] = tl[cc][r] * c;
    }
}

// ---------------- f32 batched GEMM (pinv loop): D = alpha*(A@B) + gamma*E ----------------
__global__ __launch_bounds__(256) void bgemm_kernel(const float* __restrict__ A,
                                                    const float* __restrict__ B,
                                                    float* __restrict__ D,
                                                    const float* __restrict__ E,
                                                    int M, int N, int K,
                                                    float alpha, float gamma) {
    int s = blockIdx.z;
    int bm = blockIdx.x, bn = blockIdx.y;
    A += (size_t)s * M * K; B += (size_t)s * K * N; D += (size_t)s * M * N;
    const float* Ep = E ? E + (size_t)s * M * N : nullptr;
    __shared__ float As[32][67];
    __shared__ float Bs[32][68];
    int t = threadIdx.x;
    int tm = t & 15, tn = t >> 4;
    float acc[4][4];
#pragma unroll
    for (int i = 0; i < 4; ++i)
#pragma unroll
        for (int j = 0; j < 4; ++j) acc[i][j] = 0.f;
    for (int kt = 0; kt < K; kt += 32) {
#pragma unroll
        for (int u = 0; u < 2; ++u) {
            int fid = t + 256 * u;
            int r = fid >> 3, kg = (fid & 7) << 2;
            float4 av = *(const float4*)(A + (size_t)(bm * 64 + r) * K + kt + kg);
            As[kg + 0][r] = av.x; As[kg + 1][r] = av.y; As[kg + 2][r] = av.z; As[kg + 3][r] = av.w;
            int kr = fid >> 4, cg = (fid & 15) << 2;
            float4 bv = *(const float4*)(B + (size_t)(kt + kr) * N + bn * 64 + cg);
            *(float4*)(&Bs[kr][cg]) = bv;
        }
        __syncthreads();
#pragma unroll
        for (int kk = 0; kk < 32; ++kk) {
            float a[4], bb[4];
#pragma unroll
            for (int i = 0; i < 4; ++i) a[i] = As[kk][tm * 4 + i];
#pragma unroll
            for (int j = 0; j < 4; ++j) bb[j] = Bs[kk][tn * 4 + j];
#pragma unroll
            for (int i = 0; i < 4; ++i)
#pragma unroll
                for (int j = 0; j < 4; ++j) acc[i][j] = fmaf(a[i], bb[j], acc[i][j]);
        }
        __syncthreads();
    }
#pragma unroll
    for (int i = 0; i < 4; ++i) {
        int r = bm * 64 + tm * 4 + i;
#pragma unroll
        for (int j = 0; j < 4; ++j) {
            int c = bn * 64 + tn * 4 + j;
            float val = alpha * acc[i][j];
            if (Ep) val = fmaf(gamma, Ep[(size_t)r * N + c], val);
            D[(size_t)r * N + c] = val;
        }
    }
}

// ---------------- w2t = (zc @ a3v)^T as bf16 [bh][dh=64][j=256] ----------------
__global__ __launch_bounds__(256) void bgemm_w2t(const float* __restrict__ A,
                                                 const float* __restrict__ B,
                                                 unsigned short* __restrict__ w2t) {
    const int M = 256, N = 64, K = 256;
    int s = blockIdx.z;
    int bm = blockIdx.x;
    A += (size_t)s * M * K; B += (size_t)s * K * N;
    __shared__ float As[32][67];
    __shared__ float Bs[32][68];
    int t = threadIdx.x;
    int tm = t & 15, tn = t >> 4;
    float acc[4][4];
#pragma unroll
    for (int i = 0; i < 4; ++i)
#pragma unroll
        for (int j = 0; j < 4; ++j) acc[i][j] = 0.f;
    for (int kt = 0; kt < K; kt += 32) {
#pragma unroll
        for (int u = 0; u < 2; ++u) {
            int fid = t + 256 * u;
            int r = fid >> 3, kg = (fid & 7) << 2;
            float4 av = *(const float4*)(A + (size_t)(bm * 64 + r) * K + kt + kg);
            As[kg + 0][r] = av.x; As[kg + 1][r] = av.y; As[kg + 2][r] = av.z; As[kg + 3][r] = av.w;
            int kr = fid >> 4, cg = (fid & 15) << 2;
            if (cg < N) {
                float4 bv = *(const float4*)(B + (size_t)(kt + kr) * N + cg);
                *(float4*)(&Bs[kr][cg]) = bv;
            }
        }
        __syncthreads();
#pragma unroll
        for (int kk = 0; kk < 32; ++kk) {
            float a[4], bb[4];
#pragma unroll
            for (int i = 0; i < 4; ++i) a[i] = As[kk][tm * 4 + i];
#pragma unroll
            for (int j = 0; j < 4; ++j) bb[j] = Bs[kk][(tn & 15) * 4 + j];
#pragma unroll
            for (int i = 0; i < 4; ++i)
#pragma unroll
                for (int j = 0; j < 4; ++j) acc[i][j] = fmaf(a[i], bb[j], acc[i][j]);
        }
        __syncthreads();
    }
    if (tn < 16) {
#pragma unroll
        for (int i = 0; i < 4; ++i) {
            int r = bm * 64 + tm * 4 + i;
#pragma unroll
            for (int j = 0; j < 4; ++j) {
                int c = tn * 4 + j;
                w2t[(size_t)s * 16384 + (size_t)c * 256 + r] = f2b(acc[i][j]);
            }
        }
    }
}

// ---------------- attn3@v fused-softmax MFMA (j-split partials) ----------------
__global__ __launch_bounds__(256) void attn3v_mfma(const unsigned short* __restrict__ qlb,
                                                   const unsigned short* __restrict__ kb,
                                                   const unsigned short* __restrict__ vtb,
                                                   float* __restrict__ num_part,
                                                   float* __restrict__ den_part) {
    int it = blockIdx.x, js = blockIdx.y, bh = blockIdx.z;
    __shared__ unsigned short k_lds[64][72];
    __shared__ unsigned short v_lds[64][72];
    __shared__ unsigned short p_lds[4][16][72];
    int t = threadIdx.x;
    int w = t >> 6, l = t & 63, lr = l & 15, g = l >> 4;
    int i0 = it * 64;
    const unsigned short* qp = qlb + ((size_t)(bh * 256 + i0 + w * 16 + lr)) * 64 + g * 8;
    bf16x8 aq0 = *(const bf16x8*)qp;
    bf16x8 aq1 = *(const bf16x8*)(qp + 32);
    f32x4 acc[4];
#pragma unroll
    for (int i = 0; i < 4; ++i) acc[i] = (f32x4)0.f;
    float dacc[4] = {0.f, 0.f, 0.f, 0.f};
    int srow = t >> 2, sq = t & 3;
    const size_t kbase = ((size_t)bh * 4096 + js * 1024) * 64;
    const size_t vbase = (size_t)bh * 64 * 4096 + js * 1024;
    for (int st = 0; st < 16; ++st) {
        int j0 = st * 64;
        {
            const unsigned short* src = kb + kbase + (size_t)(j0 + srow) * 64 + sq * 16;
            *(uint4*)&k_lds[srow][sq * 16]     = *(const uint4*)src;
            *(uint4*)&k_lds[srow][sq * 16 + 8] = *(const uint4*)(src + 8);
            const unsigned short* sv = vtb + vbase + (size_t)srow * 4096 + j0 + sq * 16;
            *(uint4*)&v_lds[srow][sq * 16]     = *(const uint4*)sv;
            *(uint4*)&v_lds[srow][sq * 16 + 8] = *(const uint4*)(sv + 8);
        }
        __syncthreads();
        f32x4 sacc[4];
#pragma unroll
        for (int jt = 0; jt < 4; ++jt) {
            bf16x8 bk0 = *(const bf16x8*)&k_lds[jt * 16 + lr][g * 8];
            bf16x8 bk1 = *(const bf16x8*)&k_lds[jt * 16 + lr][32 + g * 8];
            sacc[jt] = MFMA16(aq0, bk0, (f32x4)0.f);
            sacc[jt] = MFMA16(aq1, bk1, sacc[jt]);
        }
        float dr[4] = {0.f, 0.f, 0.f, 0.f};
#pragma unroll
        for (int jt = 0; jt < 4; ++jt) {
#pragma unroll
            for (int r = 0; r < 4; ++r) {
                float p = __expf(sacc[jt][r]);
                p_lds[w][g * 4 + r][jt * 16 + lr] = f2b(p);
                dr[r] += p;
            }
        }
#pragma unroll
        for (int r = 0; r < 4; ++r) {
#pragma unroll
            for (int m = 1; m < 16; m <<= 1) dr[r] += __shfl_xor(dr[r], m);
            dacc[r] += dr[r];
        }
        bf16x8 pa0 = *(const bf16x8*)&p_lds[w][lr][g * 8];
        bf16x8 pa1 = *(const bf16x8*)&p_lds[w][lr][32 + g * 8];
#pragma unroll
        for (int dt = 0; dt < 4; ++dt) {
            bf16x8 bv0 = *(const bf16x8*)&v_lds[dt * 16 + lr][g * 8];
            bf16x8 bv1 = *(const bf16x8*)&v_lds[dt * 16 + lr][32 + g * 8];
            acc[dt] = MFMA16(pa0, bv0, acc[dt]);
            acc[dt] = MFMA16(pa1, bv1, acc[dt]);
        }
        __syncthreads();
    }
    size_t obase = (size_t)(js * 32 + bh) * 256 + i0 + w * 16;
#pragma unroll
    for (int dt = 0; dt < 4; ++dt)
#pragma unroll
        for (int r = 0; r < 4; ++r)
            num_part[(obase + g * 4 + r) * 64 + dt * 16 + lr] = acc[dt][r];
    if (lr == 0) {
#pragma unroll
        for (int r = 0; r < 4; ++r) den_part[obase + g * 4 + r] = dacc[r];
    }
}

// ---------------- combine attn3v partials ----------------
__global__ void a3v_combine(const float* __restrict__ num_part,
                            const float* __restrict__ den_part,
                            float* __restrict__ a3v) {
    int idx = blockIdx.x * 256 + threadIdx.x;  // 524288
    int dh = idx & 63;
    int rest = idx >> 6;
    float n = 0, d = 0;
#pragma unroll
    for (int s = 0; s < 4; ++s) {
        n += num_part[((size_t)s * 8192 + rest) * 64 + dh];
        d += den_part[(size_t)s * 8192 + rest];
    }
    a3v[idx] = n / d;
}

// ---------------- attn1 fused-softmax MFMA @ w2t, + conv outh -> outh_bf ----------------
__global__ __launch_bounds__(256) void attn1_mfma(const unsigned short* __restrict__ qb,
                                                  const unsigned short* __restrict__ klb,
                                                  const unsigned short* __restrict__ w2t,
                                                  const float* __restrict__ outh,
                                                  unsigned short* __restrict__ outhb) {
    int it = blockIdx.x, bh = blockIdx.y;
    __shared__ unsigned short k_lds[64][72];
    __shared__ unsigned short v_lds[64][72];
    __shared__ unsigned short p_lds[4][16][72];
    int t = threadIdx.x;
    int w = t >> 6, l = t & 63, lr = l & 15, g = l >> 4;
    int i0 = it * 64;
    const unsigned short* qp = qb + ((size_t)bh * 4096 + i0 + w * 16 + lr) * 64 + g * 8;
    bf16x8 aq0 = *(const bf16x8*)qp;
    bf16x8 aq1 = *(const bf16x8*)(qp + 32);
    f32x4 acc[4];
#pragma unroll
    for (int i = 0; i < 4; ++i) acc[i] = (f32x4)0.f;
    float dacc[4] = {0.f, 0.f, 0.f, 0.f};
    int srow = t >> 2, sq = t & 3;
    for (int st = 0; st < 4; ++st) {
        int j0 = st * 64;
        {
            const unsigned short* src = klb + ((size_t)bh * 256 + j0 + srow) * 64 + sq * 16;
            *(uint4*)&k_lds[srow][sq * 16]     = *(const uint4*)src;
            *(uint4*)&k_lds[srow][sq * 16 + 8] = *(const uint4*)(src + 8);
            const unsigned short* sv = w2t + ((size_t)bh * 64 + srow) * 256 + j0 + sq * 16;
            *(uint4*)&v_lds[srow][sq * 16]     = *(const uint4*)sv;
            *(uint4*)&v_lds[srow][sq * 16 + 8] = *(const uint4*)(sv + 8);
        }
        __syncthreads();
        f32x4 sacc[4];
#pragma unroll
        for (int jt = 0; jt < 4; ++jt) {
            bf16x8 bk0 = *(const bf16x8*)&k_lds[jt * 16 + lr][g * 8];
            bf16x8 bk1 = *(const bf16x8*)&k_lds[jt * 16 + lr][32 + g * 8];
            sacc[jt] = MFMA16(aq0, bk0, (f32x4)0.f);
            sacc[jt] = MFMA16(aq1, bk1, sacc[jt]);
        }
        float dr[4] = {0.f, 0.f, 0.f, 0.f};
#pragma unroll
        for (int jt = 0; jt < 4; ++jt) {
#pragma unroll
            for (int r = 0; r < 4; ++r) {
                float p = __expf(sacc[jt][r]);
                p_lds[w][g * 4 + r][jt * 16 + lr] = f2b(p);
                dr[r] += p;
            }
        }
#pragma unroll
        for (int r = 0; r < 4; ++r) {
#pragma unroll
            for (int m = 1; m < 16; m <<= 1) dr[r] += __shfl_xor(dr[r], m);
            dacc[r] += dr[r];
        }
        bf16x8 pa0 = *(const bf16x8*)&p_lds[w][lr][g * 8];
        bf16x8 pa1 = *(const bf16x8*)&p_lds[w][lr][32 + g * 8];
#pragma unroll
        for (int dt = 0; dt < 4; ++dt) {
            bf16x8 bv0 = *(const bf16x8*)&v_lds[dt * 16 + lr][g * 8];
            bf16x8 bv1 = *(const bf16x8*)&v_lds[dt * 16 + lr][32 + g * 8];
            acc[dt] = MFMA16(pa0, bv0, acc[dt]);
            acc[dt] = MFMA16(pa1, bv1, acc[dt]);
        }
        __syncthreads();
    }
    int bb = bh >> 3, hh = bh & 7;
#pragma unroll
    for (int dt = 0; dt < 4; ++dt) {
#pragma unroll
        for (int r = 0; r < 4; ++r) {
            int row = i0 + w * 16 + g * 4 + r;
            float val = acc[dt][r] / dacc[r]
                      + outh[((size_t)bh * 4096 + row) * 64 + dt * 16 + lr];
            outhb[((size_t)(bb * 4096 + row)) * 512 + hh * 64 + dt * 16 + lr] = f2b(val);
        }
    }
}

// ---------------------------------------------------------------------------
extern "C" void kernel_launch(void* const* d_in, const int* in_sizes, int n_in,
                              void* d_out, int out_size, void* d_ws, size_t ws_size,
                              hipStream_t stream) {
    (void)in_sizes; (void)n_in; (void)out_size; (void)ws_size;
    const float* x     = (const float*)d_in[0];
    const float* ln_g  = (const float*)d_in[1];
    const float* ln_b  = (const float*)d_in[2];
    const float* w_qkv = (const float*)d_in[3];
    const float* w_out = (const float*)d_in[4];
    const float* b_out = (const float*)d_in[5];
    const float* res_w = (const float*)d_in[6];
    float* out = (float*)d_out;

    float* ws = (float*)d_ws;
    unsigned short* xnb = (unsigned short*)ws;            // 8388608 bf16
    float* outh = ws + 4194304;                           // 8388608 f32
    float* ql   = ws + 12582912;                          // 524288
    float* kl   = ws + 13107200;                          // 524288
    float* a2   = ws + 13631488;                          // 2097152
    float* z0b  = ws + 15728640;
    float* z1b  = ws + 17825792;
    float* xzb  = ws + 19922944;
    float* t1b  = ws + 22020096;
    float* t2b  = ws + 24117248;
    float* num_part = ws + 26214400;                      // 2097152
    float* den_part = ws + 28311552;                      // 32768
    float* a3v  = ws + 28344320;                          // 524288
    unsigned* scal = (unsigned*)(ws + 28868608);          // 1 (+pad)
    unsigned short* qb    = (unsigned short*)(ws + 28868612);
    unsigned short* kb    = (unsigned short*)(ws + 33062916);
    unsigned short* vb    = (unsigned short*)(ws + 37257220);
    unsigned short* vtb   = (unsigned short*)(ws + 41451524);
    unsigned short* outhb = (unsigned short*)(ws + 45645828);
    unsigned short* qlb   = (unsigned short*)(ws + 49840132);
    unsigned short* klb   = (unsigned short*)(ws + 50102276);
    unsigned short* wqkvb = (unsigned short*)(ws + 50364420);
    unsigned short* woutb = (unsigned short*)(ws + 50757636);
    unsigned short* w2tb  = (unsigned short*)(ws + 50888708);

    hipMemsetAsync(scal, 0, 4, stream);
    ln_kernel<<<16384, 256, 0, stream>>>(x, ln_g, ln_b, xnb);
    cvt_kernel<<<4096, 256, 0, stream>>>(w_qkv, w_out, wqkvb, woutb);
    gemm_mfma<0><<<dim3(128, 12), 256, 0, stream>>>(xnb, wqkvb, qb, kb, vb, nullptr, nullptr, nullptr);
    vt_kernel<<<dim3(64, 32), 256, 0, stream>>>(vb, vtb);
    landmark_kernel<<<2048, 256, 0, stream>>>(qb, kb, ql, kl, qlb, klb);
    conv_kernel<<<32768, 256, 0, stream>>>(vb, res_w, outh);
    attn2_kernel<<<8192, 256, 0, stream>>>(ql, kl, a2);
    colmax_kernel<<<32, 256, 0, stream>>>(a2, scal);
    z0_kernel<<<dim3(4, 4, 32), 256, 0, stream>>>(a2, (const float*)scal, z0b);
    float* zc = z0b; float* za = z1b;
    for (int itr = 0; itr < 6; ++itr) {
        bgemm_kernel<<<dim3(4, 4, 32), 256, 0, stream>>>(a2, zc, xzb, nullptr, 256, 256, 256, 1.f, 0.f);
        bgemm_kernel<<<dim3(4, 4, 32), 256, 0, stream>>>(xzb, xzb, t1b, xzb, 256, 256, 256, -1.f, 7.f);
        bgemm_kernel<<<dim3(4, 4, 32), 256, 0, stream>>>(xzb, t1b, t2b, xzb, 256, 256, 256, -1.f, 15.f);
        bgemm_kernel<<<dim3(4, 4, 32), 256, 0, stream>>>(zc, t2b, za, zc, 256, 256, 256, -0.25f, 3.25f);
        float* tmp = zc; zc = za; za = tmp;
    }
    attn3v_mfma<<<dim3(4, 4, 32), 256, 0, stream>>>(qlb, kb, vtb, num_part, den_part);
    a3v_combine<<<2048, 256, 0, stream>>>(num_part, den_part, a3v);
    bgemm_w2t<<<dim3(4, 1, 32), 256, 0, stream>>>(zc, a3v, w2tb);
    attn1_mfma<<<dim3(64, 32), 256, 0, stream>>>(qb, klb, w2tb, outh, outhb);
    gemm_mfma<1><<<dim3(128, 4), 256, 0, stream>>>(outhb, woutb, nullptr, nullptr, nullptr, b_out, x, out);
}

// Round 4
// 815.262 us; speedup vs baseline: 2.7145x; 1.7183x over previous
//
#include <hip/hip_runtime.h>
#include <hip/hip_bf16.h>
#include <math.h>

// ---------------------------------------------------------------------------
// Nystrom attention layer. Round 4: pinv Newton-Schulz via split-precision
// bf16x2 MFMA (Ah@Bh + Ah@Bl + Al@Bh ~ f32 accuracy); conv vectorized.
// b=4, n=4096, d=512, h=8, dh=64, m=256 landmarks, l=16, conv K=33.
// out = attn1 @ (pinv(attn2) @ (attn3 @ v))  (re-associated)
// ---------------------------------------------------------------------------

using bf16x8 = __attribute__((ext_vector_type(8))) short;
using f32x4  = __attribute__((ext_vector_type(4))) float;

static __device__ __forceinline__ f32x4 MFMA16(bf16x8 a, bf16x8 b, f32x4 c) {
    return __builtin_amdgcn_mfma_f32_16x16x32_bf16(a, b, c, 0, 0, 0);
}
static __device__ __forceinline__ unsigned short f2b(float f) {
    union { float f; unsigned u; } x; x.f = f;
    unsigned r = x.u + 0x7FFFu + ((x.u >> 16) & 1u);
    return (unsigned short)(r >> 16);
}
static __device__ __forceinline__ float b2f(unsigned short b) {
    union { unsigned u; float f; } x; x.u = ((unsigned)b) << 16; return x.f;
}

// ---------------- LayerNorm: 16384 rows x 512, bf16 out ----------------
__global__ __launch_bounds__(256) void ln_kernel(const float* __restrict__ x,
                                                 const float* __restrict__ g,
                                                 const float* __restrict__ b,
                                                 unsigned short* __restrict__ xn) {
    int row = blockIdx.x;
    const float* xr = x + (size_t)row * 512;
    int t = threadIdx.x;
    float v0 = xr[t], v1 = xr[t + 256];
    __shared__ float red[4];
    float s = v0 + v1;
#pragma unroll
    for (int off = 32; off; off >>= 1) s += __shfl_down(s, off);
    if ((t & 63) == 0) red[t >> 6] = s;
    __syncthreads();
    float mean = (red[0] + red[1] + red[2] + red[3]) * (1.0f / 512.0f);
    __syncthreads();
    float d0 = v0 - mean, d1 = v1 - mean;
    float q2 = d0 * d0 + d1 * d1;
#pragma unroll
    for (int off = 32; off; off >>= 1) q2 += __shfl_down(q2, off);
    if ((t & 63) == 0) red[t >> 6] = q2;
    __syncthreads();
    float var = (red[0] + red[1] + red[2] + red[3]) * (1.0f / 512.0f);
    float inv = rsqrtf(var + 1e-5f);
    unsigned short* o = xn + (size_t)row * 512;
    o[t]       = f2b(d0 * inv * g[t]       + b[t]);
    o[t + 256] = f2b(d1 * inv * g[t + 256] + b[t + 256]);
}

// ---------------- weight conversion f32 -> bf16 ----------------
__global__ void cvt_kernel(const float* __restrict__ wqkv, const float* __restrict__ wout,
                           unsigned short* __restrict__ wqkvb, unsigned short* __restrict__ woutb) {
    int idx = blockIdx.x * 256 + threadIdx.x;   // 1048576
    if (idx < 786432) wqkvb[idx] = f2b(wqkv[idx]);
    else woutb[idx - 786432] = f2b(wout[idx - 786432]);
}

// ---------------- bf16 MFMA GEMM: C[M,*] = A[M,512] @ Bw[N,512]^T ----------------
// MODE 0: qkv (scatter q*0.125 / k / v bf16, [bh][n][dh])
// MODE 1: proj (out = acc + bias + x residual, f32 [16384][512])
template<int MODE>
__global__ __launch_bounds__(256) void gemm_mfma(const unsigned short* __restrict__ A,
                                                 const unsigned short* __restrict__ Bw,
                                                 unsigned short* __restrict__ qb,
                                                 unsigned short* __restrict__ kb,
                                                 unsigned short* __restrict__ vb,
                                                 const float* __restrict__ bias,
                                                 const float* __restrict__ xres,
                                                 float* __restrict__ out) {
    const int K = 512;
    __shared__ unsigned short As[128][40];
    __shared__ unsigned short Bs[128][40];
    int t = threadIdx.x;
    int w = t >> 6, l = t & 63, lr = l & 15, g = l >> 4;
    int wm = w >> 1, wn = w & 1;
    int row0 = blockIdx.x * 128, col0 = blockIdx.y * 128;
    f32x4 acc[4][4];
#pragma unroll
    for (int i = 0; i < 4; ++i)
#pragma unroll
        for (int j = 0; j < 4; ++j) acc[i][j] = (f32x4)0.f;
    int srow = t >> 1, sh = t & 1;
    for (int kt = 0; kt < K; kt += 32) {
        const unsigned short* as = A + (size_t)(row0 + srow) * K + kt + sh * 16;
        *(uint4*)&As[srow][sh * 16]     = *(const uint4*)as;
        *(uint4*)&As[srow][sh * 16 + 8] = *(const uint4*)(as + 8);
        const unsigned short* bs = Bw + (size_t)(col0 + srow) * K + kt + sh * 16;
        *(uint4*)&Bs[srow][sh * 16]     = *(const uint4*)bs;
        *(uint4*)&Bs[srow][sh * 16 + 8] = *(const uint4*)(bs + 8);
        __syncthreads();
        bf16x8 a[4], b[4];
#pragma unroll
        for (int mt = 0; mt < 4; ++mt) a[mt] = *(const bf16x8*)&As[wm * 64 + mt * 16 + lr][g * 8];
#pragma unroll
        for (int nt = 0; nt < 4; ++nt) b[nt] = *(const bf16x8*)&Bs[wn * 64 + nt * 16 + lr][g * 8];
#pragma unroll
        for (int mt = 0; mt < 4; ++mt)
#pragma unroll
            for (int nt = 0; nt < 4; ++nt) acc[mt][nt] = MFMA16(a[mt], b[nt], acc[mt][nt]);
        __syncthreads();
    }
#pragma unroll
    for (int mt = 0; mt < 4; ++mt) {
#pragma unroll
        for (int nt = 0; nt < 4; ++nt) {
#pragma unroll
            for (int r = 0; r < 4; ++r) {
                int row = row0 + wm * 64 + mt * 16 + g * 4 + r;
                int col = col0 + wn * 64 + nt * 16 + lr;
                float val = acc[mt][nt][r];
                if (MODE == 0) {
                    int bb = row >> 12, nn = row & 4095;
                    int which = col >> 9, rem = col & 511;
                    int hh = rem >> 6, dd = rem & 63;
                    size_t di = (((size_t)(bb * 8 + hh)) * 4096 + nn) * 64 + dd;
                    if (which == 0) qb[di] = f2b(val * 0.125f);
                    else if (which == 1) kb[di] = f2b(val);
                    else vb[di] = f2b(val);
                } else {
                    out[(size_t)row * 512 + col] = val + bias[col] + xres[(size_t)row * 512 + col];
                }
            }
        }
    }
}

// ---------------- transpose v_bf -> vt_bf [bh][dh][n] ----------------
__global__ __launch_bounds__(256) void vt_kernel(const unsigned short* __restrict__ vb,
                                                 unsigned short* __restrict__ vtb) {
    int n0 = blockIdx.x * 64, bh = blockIdx.y;
    __shared__ unsigned short tl[64][72];
    int t = threadIdx.x;
#pragma unroll
    for (int u = 0; u < 2; ++u) {
        int cid = t * 2 + u;
        int r = cid >> 3, c8 = (cid & 7) << 3;
        uint4 vv = *(const uint4*)(vb + ((size_t)bh * 4096 + n0 + r) * 64 + c8);
        unsigned short* pv = (unsigned short*)&vv;
#pragma unroll
        for (int i = 0; i < 8; ++i) tl[c8 + i][r] = pv[i];
    }
    __syncthreads();
#pragma unroll
    for (int u = 0; u < 2; ++u) {
        int cid = t * 2 + u;
        int r = cid >> 3, c8 = (cid & 7) << 3;
        *(uint4*)(vtb + ((size_t)bh * 64 + r) * 4096 + n0 + c8) = *(uint4*)&tl[r][c8];
    }
}

// ---------------- landmark means (l=16), f32 + bf16 outs ----------------
__global__ void landmark_kernel(const unsigned short* __restrict__ q,
                                const unsigned short* __restrict__ k,
                                float* __restrict__ ql, float* __restrict__ kl,
                                unsigned short* __restrict__ qlb, unsigned short* __restrict__ klb) {
    int idx = blockIdx.x * 256 + threadIdx.x;   // 524288
    int dh = idx & 63, mi = (idx >> 6) & 255, bh = idx >> 14;
    size_t base = ((size_t)bh * 4096 + mi * 16) * 64 + dh;
    float sq = 0, sk = 0;
#pragma unroll
    for (int j = 0; j < 16; ++j) { sq += b2f(q[base + (size_t)j * 64]); sk += b2f(k[base + (size_t)j * 64]); }
    sq *= 0.0625f; sk *= 0.0625f;
    ql[idx] = sq; kl[idx] = sk;
    qlb[idx] = f2b(sq); klb[idx] = f2b(sk);
}

// ---------------- depthwise conv residual -> outh (f32 [bh][n][dh]) ----------------
// thread = 8 consecutive dh (one uint4 of bf16 per tap), 8 outputs
__global__ __launch_bounds__(256) void conv_kernel(const unsigned short* __restrict__ v,
                                                   const float* __restrict__ rw,
                                                   float* __restrict__ outh) {
    int idx = blockIdx.x * 256 + threadIdx.x;   // 1048576
    int o = idx & 7, n = (idx >> 3) & 4095, bh = idx >> 15;
    int h = bh & 7;
    const unsigned short* vb = v + (((size_t)bh) << 18) + o * 8;
    float acc[8];
#pragma unroll
    for (int i = 0; i < 8; ++i) acc[i] = 0.f;
#pragma unroll
    for (int tt = 0; tt < 33; ++tt) {
        int j = n + tt - 16;
        if (j >= 0 && j < 4096) {
            uint4 pv = *(const uint4*)(vb + (size_t)j * 64);
            const unsigned short* pp = (const unsigned short*)&pv;
            float wgt = rw[h * 33 + tt];
#pragma unroll
            for (int i = 0; i < 8; ++i) acc[i] = fmaf(wgt, b2f(pp[i]), acc[i]);
        }
    }
    float4 r0, r1;
    r0.x = acc[0]; r0.y = acc[1]; r0.z = acc[2]; r0.w = acc[3];
    r1.x = acc[4]; r1.y = acc[5]; r1.z = acc[6]; r1.w = acc[7];
    *(float4*)(outh + (size_t)idx * 8)     = r0;
    *(float4*)(outh + (size_t)idx * 8 + 4) = r1;
}

// ---------------- attn2 = softmax(ql @ kl^T), f32 ----------------
__global__ __launch_bounds__(256) void attn2_kernel(const float* __restrict__ ql,
                                                    const float* __restrict__ kl,
                                                    float* __restrict__ a2) {
    int bh = blockIdx.x >> 8, i = blockIdx.x & 255;
    int t = threadIdx.x;
    __shared__ float qrow[64];
    __shared__ float red[4];
    if (t < 64) qrow[t] = ql[((size_t)bh * 256 + i) * 64 + t];
    __syncthreads();
    const float* krow = kl + ((size_t)bh * 256 + t) * 64;
    float s = 0;
#pragma unroll
    for (int c = 0; c < 64; c += 4) {
        float4 kv = *(const float4*)(krow + c);
        s = fmaf(qrow[c], kv.x, s); s = fmaf(qrow[c + 1], kv.y, s);
        s = fmaf(qrow[c + 2], kv.z, s); s = fmaf(qrow[c + 3], kv.w, s);
    }
    float p = __expf(s);    // logits are O(0.05): no max-subtraction needed
    float sum = p;
#pragma unroll
    for (int off = 32; off; off >>= 1) sum += __shfl_down(sum, off);
    if ((t & 63) == 0) red[t >> 6] = sum;
    __syncthreads();
    float tot = red[0] + red[1] + red[2] + red[3];
    a2[((size_t)bh * 256 + i) * 256 + t] = p / tot;
}

// ---------------- max column-sum of attn2 (row-sums are exactly 1) ----------------
__global__ __launch_bounds__(256) void colmax_kernel(const float* __restrict__ a2,
                                                     unsigned* __restrict__ scal) {
    int bh = blockIdx.x, t = threadIdx.x;
    const float* m = a2 + (size_t)bh * 65536;
    float cs = 0;
    for (int i = 0; i < 256; ++i) cs += m[i * 256 + t];
#pragma unroll
    for (int off = 32; off; off >>= 1) cs = fmaxf(cs, __shfl_down(cs, off));
    __shared__ float red[4];
    if ((t & 63) == 0) red[t >> 6] = cs;
    __syncthreads();
    if (t == 0) {
        float mx = fmaxf(fmaxf(red[0], red[1]), fmaxf(red[2], red[3]));
        atomicMax(scal, __float_as_uint(mx));
    }
}

// ---------------- z0 = attn2^T / colsum_max ----------------
__global__ __launch_bounds__(256) void z0_kernel(const float* __restrict__ a2,
                                                 const float* __restrict__ scal,
                                                 float* __restrict__ z) {
    int bh = blockIdx.z;
    int ib = blockIdx.x * 64, jb = blockIdx.y * 64;
    __shared__ float tl[64][65];
    float c = 1.0f / *scal;
    int t = threadIdx.x;
#pragma unroll
    for (int u = 0; u < 16; ++u) {
        int idx = t + 256 * u;
        int r = idx >> 6, cc = idx & 63;
        tl[r][cc] = a2[(size_t)bh * 65536 + (size_t)(jb + r) * 256 + ib + cc];
    }
    __syncthreads();
#pragma unroll
    for (int u = 0; u < 16; ++u) {
        int idx = t + 256 * u;
        int r = idx >> 6, cc = idx & 63;
        z[(size_t)bh * 65536 + (size_t)(ib + r) * 256 + jb + cc] = tl[cc][r] * c;
    }
}

// ---------------- split-precision bf16x2 MFMA batched GEMM (pinv loop) ----------------
// fixed 256x256x256 per batch; D = alpha*(A@B) + gamma*E
// A@B ~ Ah@Bh + Ah@Bl + Al@Bh  (hi/lo bf16 split, ~1e-5 relative error)
__global__ __launch_bounds__(256) void bgemm_mfma_split(const float* __restrict__ A,
                                                        const float* __restrict__ B,
                                                        float* __restrict__ D,
                                                        const float* __restrict__ E,
                                                        float alpha, float gamma) {
    int s = blockIdx.z;
    A += (size_t)s * 65536; B += (size_t)s * 65536; D += (size_t)s * 65536;
    const float* Ep = E ? E + (size_t)s * 65536 : nullptr;
    __shared__ unsigned short Ah[64][40], Al[64][40], Bh[64][40], Bl[64][40];
    int t = threadIdx.x;
    int w = t >> 6, l = t & 63, lr = l & 15, g = l >> 4;
    int wm = w >> 1, wn = w & 1;
    int bm = blockIdx.x, bn = blockIdx.y;
    f32x4 acc[2][2];
#pragma unroll
    for (int i = 0; i < 2; ++i)
#pragma unroll
        for (int j = 0; j < 2; ++j) acc[i][j] = (f32x4)0.f;
    int arow = t >> 2, akq = (t & 3) * 8;
    int bkr = t >> 3, bnq = (t & 7) * 8;
    for (int kt = 0; kt < 256; kt += 32) {
        const float* ap = A + (size_t)(bm * 64 + arow) * 256 + kt + akq;
        float4 a0 = *(const float4*)ap;
        float4 a1 = *(const float4*)(ap + 4);
        float av[8] = {a0.x, a0.y, a0.z, a0.w, a1.x, a1.y, a1.z, a1.w};
#pragma unroll
        for (int i = 0; i < 8; ++i) {
            unsigned short hi = f2b(av[i]);
            Ah[arow][akq + i] = hi;
            Al[arow][akq + i] = f2b(av[i] - b2f(hi));
        }
        const float* bp = B + (size_t)(kt + bkr) * 256 + bn * 64 + bnq;
        float4 b0 = *(const float4*)bp;
        float4 b1 = *(const float4*)(bp + 4);
        float bv[8] = {b0.x, b0.y, b0.z, b0.w, b1.x, b1.y, b1.z, b1.w};
#pragma unroll
        for (int i = 0; i < 8; ++i) {
            unsigned short hi = f2b(bv[i]);
            Bh[bnq + i][bkr] = hi;
            Bl[bnq + i][bkr] = f2b(bv[i] - b2f(hi));
        }
        __syncthreads();
        bf16x8 ah[2], al_[2], bh[2], bl_[2];
#pragma unroll
        for (int mf = 0; mf < 2; ++mf) {
            ah[mf]  = *(const bf16x8*)&Ah[wm * 32 + mf * 16 + lr][g * 8];
            al_[mf] = *(const bf16x8*)&Al[wm * 32 + mf * 16 + lr][g * 8];
        }
#pragma unroll
        for (int nf = 0; nf < 2; ++nf) {
            bh[nf]  = *(const bf16x8*)&Bh[wn * 32 + nf * 16 + lr][g * 8];
            bl_[nf] = *(const bf16x8*)&Bl[wn * 32 + nf * 16 + lr][g * 8];
        }
#pragma unroll
        for (int mf = 0; mf < 2; ++mf)
#pragma unroll
            for (int nf = 0; nf < 2; ++nf) {
                acc[mf][nf] = MFMA16(ah[mf], bh[nf], acc[mf][nf]);
                acc[mf][nf] = MFMA16(ah[mf], bl_[nf], acc[mf][nf]);
                acc[mf][nf] = MFMA16(al_[mf], bh[nf], acc[mf][nf]);
            }
        __syncthreads();
    }
#pragma unroll
    for (int mf = 0; mf < 2; ++mf) {
#pragma unroll
        for (int nf = 0; nf < 2; ++nf) {
#pragma unroll
            for (int r = 0; r < 4; ++r) {
                int row = bm * 64 + wm * 32 + mf * 16 + g * 4 + r;
                int col = bn * 64 + wn * 32 + nf * 16 + lr;
                float val = alpha * acc[mf][nf][r];
                if (Ep) val = fmaf(gamma, Ep[(size_t)row * 256 + col], val);
                D[(size_t)row * 256 + col] = val;
            }
        }
    }
}

// ---------------- w2t = (zc @ a3v)^T as bf16 [bh][dh=64][j=256] ----------------
__global__ __launch_bounds__(256) void bgemm_w2t(const float* __restrict__ A,
                                                 const float* __restrict__ B,
                                                 unsigned short* __restrict__ w2t) {
    const int M = 256, N = 64, K = 256;
    int s = blockIdx.z;
    int bm = blockIdx.x;
    A += (size_t)s * M * K; B += (size_t)s * K * N;
    __shared__ float As[32][67];
    __shared__ float Bs[32][68];
    int t = threadIdx.x;
    int tm = t & 15, tn = t >> 4;
    float acc[4][4];
#pragma unroll
    for (int i = 0; i < 4; ++i)
#pragma unroll
        for (int j = 0; j < 4; ++j) acc[i][j] = 0.f;
    for (int kt = 0; kt < K; kt += 32) {
#pragma unroll
        for (int u = 0; u < 2; ++u) {
            int fid = t + 256 * u;
            int r = fid >> 3, kg = (fid & 7) << 2;
            float4 av = *(const float4*)(A + (size_t)(bm * 64 + r) * K + kt + kg);
            As[kg + 0][r] = av.x; As[kg + 1][r] = av.y; As[kg + 2][r] = av.z; As[kg + 3][r] = av.w;
            int kr = fid >> 4, cg = (fid & 15) << 2;
            if (cg < N) {
                float4 bv = *(const float4*)(B + (size_t)(kt + kr) * N + cg);
                *(float4*)(&Bs[kr][cg]) = bv;
            }
        }
        __syncthreads();
#pragma unroll
        for (int kk = 0; kk < 32; ++kk) {
            float a[4], bb[4];
#pragma unroll
            for (int i = 0; i < 4; ++i) a[i] = As[kk][tm * 4 + i];
#pragma unroll
            for (int j = 0; j < 4; ++j) bb[j] = Bs[kk][(tn & 15) * 4 + j];
#pragma unroll
            for (int i = 0; i < 4; ++i)
#pragma unroll
                for (int j = 0; j < 4; ++j) acc[i][j] = fmaf(a[i], bb[j], acc[i][j]);
        }
        __syncthreads();
    }
    if (tn < 16) {
#pragma unroll
        for (int i = 0; i < 4; ++i) {
            int r = bm * 64 + tm * 4 + i;
#pragma unroll
            for (int j = 0; j < 4; ++j) {
                int c = tn * 4 + j;
                w2t[(size_t)s * 16384 + (size_t)c * 256 + r] = f2b(acc[i][j]);
            }
        }
    }
}

// ---------------- attn3@v fused-softmax MFMA (j-split partials) ----------------
__global__ __launch_bounds__(256) void attn3v_mfma(const unsigned short* __restrict__ qlb,
                                                   const unsigned short* __restrict__ kb,
                                                   const unsigned short* __restrict__ vtb,
                                                   float* __restrict__ num_part,
                                                   float* __restrict__ den_part) {
    int it = blockIdx.x, js = blockIdx.y, bh = blockIdx.z;
    __shared__ unsigned short k_lds[64][72];
    __shared__ unsigned short v_lds[64][72];
    __shared__ unsigned short p_lds[4][16][72];
    int t = threadIdx.x;
    int w = t >> 6, l = t & 63, lr = l & 15, g = l >> 4;
    int i0 = it * 64;
    const unsigned short* qp = qlb + ((size_t)(bh * 256 + i0 + w * 16 + lr)) * 64 + g * 8;
    bf16x8 aq0 = *(const bf16x8*)qp;
    bf16x8 aq1 = *(const bf16x8*)(qp + 32);
    f32x4 acc[4];
#pragma unroll
    for (int i = 0; i < 4; ++i) acc[i] = (f32x4)0.f;
    float dacc[4] = {0.f, 0.f, 0.f, 0.f};
    int srow = t >> 2, sq = t & 3;
    const size_t kbase = ((size_t)bh * 4096 + js * 1024) * 64;
    const size_t vbase = (size_t)bh * 64 * 4096 + js * 1024;
    for (int st = 0; st < 16; ++st) {
        int j0 = st * 64;
        {
            const unsigned short* src = kb + kbase + (size_t)(j0 + srow) * 64 + sq * 16;
            *(uint4*)&k_lds[srow][sq * 16]     = *(const uint4*)src;
            *(uint4*)&k_lds[srow][sq * 16 + 8] = *(const uint4*)(src + 8);
            const unsigned short* sv = vtb + vbase + (size_t)srow * 4096 + j0 + sq * 16;
            *(uint4*)&v_lds[srow][sq * 16]     = *(const uint4*)sv;
            *(uint4*)&v_lds[srow][sq * 16 + 8] = *(const uint4*)(sv + 8);
        }
        __syncthreads();
        f32x4 sacc[4];
#pragma unroll
        for (int jt = 0; jt < 4; ++jt) {
            bf16x8 bk0 = *(const bf16x8*)&k_lds[jt * 16 + lr][g * 8];
            bf16x8 bk1 = *(const bf16x8*)&k_lds[jt * 16 + lr][32 + g * 8];
            sacc[jt] = MFMA16(aq0, bk0, (f32x4)0.f);
            sacc[jt] = MFMA16(aq1, bk1, sacc[jt]);
        }
        float dr[4] = {0.f, 0.f, 0.f, 0.f};
#pragma unroll
        for (int jt = 0; jt < 4; ++jt) {
#pragma unroll
            for (int r = 0; r < 4; ++r) {
                float p = __expf(sacc[jt][r]);
                p_lds[w][g * 4 + r][jt * 16 + lr] = f2b(p);
                dr[r] += p;
            }
        }
#pragma unroll
        for (int r = 0; r < 4; ++r) {
#pragma unroll
            for (int m = 1; m < 16; m <<= 1) dr[r] += __shfl_xor(dr[r], m);
            dacc[r] += dr[r];
        }
        bf16x8 pa0 = *(const bf16x8*)&p_lds[w][lr][g * 8];
        bf16x8 pa1 = *(const bf16x8*)&p_lds[w][lr][32 + g * 8];
#pragma unroll
        for (int dt = 0; dt < 4; ++dt) {
            bf16x8 bv0 = *(const bf16x8*)&v_lds[dt * 16 + lr][g * 8];
            bf16x8 bv1 = *(const bf16x8*)&v_lds[dt * 16 + lr][32 + g * 8];
            acc[dt] = MFMA16(pa0, bv0, acc[dt]);
            acc[dt] = MFMA16(pa1, bv1, acc[dt]);
        }
        __syncthreads();
    }
    size_t obase = (size_t)(js * 32 + bh) * 256 + i0 + w * 16;
#pragma unroll
    for (int dt = 0; dt < 4; ++dt)
#pragma unroll
        for (int r = 0; r < 4; ++r)
            num_part[(obase + g * 4 + r) * 64 + dt * 16 + lr] = acc[dt][r];
    if (lr == 0) {
#pragma unroll
        for (int r = 0; r < 4; ++r) den_part[obase + g * 4 + r] = dacc[r];
    }
}

// ---------------- combine attn3v partials ----------------
__global__ void a3v_combine(const float* __restrict__ num_part,
                            const float* __restrict__ den_part,
                            float* __restrict__ a3v) {
    int idx = blockIdx.x * 256 + threadIdx.x;  // 524288
    int dh = idx & 63;
    int rest = idx >> 6;
    float n = 0, d = 0;
#pragma unroll
    for (int s = 0; s < 4; ++s) {
        n += num_part[((size_t)s * 8192 + rest) * 64 + dh];
        d += den_part[(size_t)s * 8192 + rest];
    }
    a3v[idx] = n / d;
}

// ---------------- attn1 fused-softmax MFMA @ w2t, + conv outh -> outh_bf ----------------
__global__ __launch_bounds__(256) void attn1_mfma(const unsigned short* __restrict__ qb,
                                                  const unsigned short* __restrict__ klb,
                                                  const unsigned short* __restrict__ w2t,
                                                  const float* __restrict__ outh,
                                                  unsigned short* __restrict__ outhb) {
    int it = blockIdx.x, bh = blockIdx.y;
    __shared__ unsigned short k_lds[64][72];
    __shared__ unsigned short v_lds[64][72];
    __shared__ unsigned short p_lds[4][16][72];
    int t = threadIdx.x;
    int w = t >> 6, l = t & 63, lr = l & 15, g = l >> 4;
    int i0 = it * 64;
    const unsigned short* qp = qb + ((size_t)bh * 4096 + i0 + w * 16 + lr) * 64 + g * 8;
    bf16x8 aq0 = *(const bf16x8*)qp;
    bf16x8 aq1 = *(const bf16x8*)(qp + 32);
    f32x4 acc[4];
#pragma unroll
    for (int i = 0; i < 4; ++i) acc[i] = (f32x4)0.f;
    float dacc[4] = {0.f, 0.f, 0.f, 0.f};
    int srow = t >> 2, sq = t & 3;
    for (int st = 0; st < 4; ++st) {
        int j0 = st * 64;
        {
            const unsigned short* src = klb + ((size_t)bh * 256 + j0 + srow) * 64 + sq * 16;
            *(uint4*)&k_lds[srow][sq * 16]     = *(const uint4*)src;
            *(uint4*)&k_lds[srow][sq * 16 + 8] = *(const uint4*)(src + 8);
            const unsigned short* sv = w2t + ((size_t)bh * 64 + srow) * 256 + j0 + sq * 16;
            *(uint4*)&v_lds[srow][sq * 16]     = *(const uint4*)sv;
            *(uint4*)&v_lds[srow][sq * 16 + 8] = *(const uint4*)(sv + 8);
        }
        __syncthreads();
        f32x4 sacc[4];
#pragma unroll
        for (int jt = 0; jt < 4; ++jt) {
            bf16x8 bk0 = *(const bf16x8*)&k_lds[jt * 16 + lr][g * 8];
            bf16x8 bk1 = *(const bf16x8*)&k_lds[jt * 16 + lr][32 + g * 8];
            sacc[jt] = MFMA16(aq0, bk0, (f32x4)0.f);
            sacc[jt] = MFMA16(aq1, bk1, sacc[jt]);
        }
        float dr[4] = {0.f, 0.f, 0.f, 0.f};
#pragma unroll
        for (int jt = 0; jt < 4; ++jt) {
#pragma unroll
            for (int r = 0; r < 4; ++r) {
                float p = __expf(sacc[jt][r]);
                p_lds[w][g * 4 + r][jt * 16 + lr] = f2b(p);
                dr[r] += p;
            }
        }
#pragma unroll
        for (int r = 0; r < 4; ++r) {
#pragma unroll
            for (int m = 1; m < 16; m <<= 1) dr[r] += __shfl_xor(dr[r], m);
            dacc[r] += dr[r];
        }
        bf16x8 pa0 = *(const bf16x8*)&p_lds[w][lr][g * 8];
        bf16x8 pa1 = *(const bf16x8*)&p_lds[w][lr][32 + g * 8];
#pragma unroll
        for (int dt = 0; dt < 4; ++dt) {
            bf16x8 bv0 = *(const bf16x8*)&v_lds[dt * 16 + lr][g * 8];
            bf16x8 bv1 = *(const bf16x8*)&v_lds[dt * 16 + lr][32 + g * 8];
            acc[dt] = MFMA16(pa0, bv0, acc[dt]);
            acc[dt] = MFMA16(pa1, bv1, acc[dt]);
        }
        __syncthreads();
    }
    int bb = bh >> 3, hh = bh & 7;
#pragma unroll
    for (int dt = 0; dt < 4; ++dt) {
#pragma unroll
        for (int r = 0; r < 4; ++r) {
            int row = i0 + w * 16 + g * 4 + r;
            float val = acc[dt][r] / dacc[r]
                      + outh[((size_t)bh * 4096 + row) * 64 + dt * 16 + lr];
            outhb[((size_t)(bb * 4096 + row)) * 512 + hh * 64 + dt * 16 + lr] = f2b(val);
        }
    }
}

// ---------------------------------------------------------------------------
extern "C" void kernel_launch(void* const* d_in, const int* in_sizes, int n_in,
                              void* d_out, int out_size, void* d_ws, size_t ws_size,
                              hipStream_t stream) {
    (void)in_sizes; (void)n_in; (void)out_size; (void)ws_size;
    const float* x     = (const float*)d_in[0];
    const float* ln_g  = (const float*)d_in[1];
    const float* ln_b  = (const float*)d_in[2];
    const float* w_qkv = (const float*)d_in[3];
    const float* w_out = (const float*)d_in[4];
    const float* b_out = (const float*)d_in[5];
    const float* res_w = (const float*)d_in[6];
    float* out = (float*)d_out;

    float* ws = (float*)d_ws;
    unsigned short* xnb = (unsigned short*)ws;            // 8388608 bf16
    float* outh = ws + 4194304;                           // 8388608 f32
    float* ql   = ws + 12582912;                          // 524288
    float* kl   = ws + 13107200;                          // 524288
    float* a2   = ws + 13631488;                          // 2097152
    float* z0b  = ws + 15728640;
    float* z1b  = ws + 17825792;
    float* xzb  = ws + 19922944;
    float* t1b  = ws + 22020096;
    float* t2b  = ws + 24117248;
    float* num_part = ws + 26214400;                      // 2097152
    float* den_part = ws + 28311552;                      // 32768
    float* a3v  = ws + 28344320;                          // 524288
    unsigned* scal = (unsigned*)(ws + 28868608);          // 1 (+pad)
    unsigned short* qb    = (unsigned short*)(ws + 28868612);
    unsigned short* kb    = (unsigned short*)(ws + 33062916);
    unsigned short* vb    = (unsigned short*)(ws + 37257220);
    unsigned short* vtb   = (unsigned short*)(ws + 41451524);
    unsigned short* outhb = (unsigned short*)(ws + 45645828);
    unsigned short* qlb   = (unsigned short*)(ws + 49840132);
    unsigned short* klb   = (unsigned short*)(ws + 50102276);
    unsigned short* wqkvb = (unsigned short*)(ws + 50364420);
    unsigned short* woutb = (unsigned short*)(ws + 50757636);
    unsigned short* w2tb  = (unsigned short*)(ws + 50888708);

    hipMemsetAsync(scal, 0, 4, stream);
    ln_kernel<<<16384, 256, 0, stream>>>(x, ln_g, ln_b, xnb);
    cvt_kernel<<<4096, 256, 0, stream>>>(w_qkv, w_out, wqkvb, woutb);
    gemm_mfma<0><<<dim3(128, 12), 256, 0, stream>>>(xnb, wqkvb, qb, kb, vb, nullptr, nullptr, nullptr);
    vt_kernel<<<dim3(64, 32), 256, 0, stream>>>(vb, vtb);
    landmark_kernel<<<2048, 256, 0, stream>>>(qb, kb, ql, kl, qlb, klb);
    conv_kernel<<<4096, 256, 0, stream>>>(vb, res_w, outh);
    attn2_kernel<<<8192, 256, 0, stream>>>(ql, kl, a2);
    colmax_kernel<<<32, 256, 0, stream>>>(a2, scal);
    z0_kernel<<<dim3(4, 4, 32), 256, 0, stream>>>(a2, (const float*)scal, z0b);
    float* zc = z0b; float* za = z1b;
    for (int itr = 0; itr < 6; ++itr) {
        bgemm_mfma_split<<<dim3(4, 4, 32), 256, 0, stream>>>(a2, zc, xzb, nullptr, 1.f, 0.f);
        bgemm_mfma_split<<<dim3(4, 4, 32), 256, 0, stream>>>(xzb, xzb, t1b, xzb, -1.f, 7.f);
        bgemm_mfma_split<<<dim3(4, 4, 32), 256, 0, stream>>>(xzb, t1b, t2b, xzb, -1.f, 15.f);
        bgemm_mfma_split<<<dim3(4, 4, 32), 256, 0, stream>>>(zc, t2b, za, zc, -0.25f, 3.25f);
        float* tmp = zc; zc = za; za = tmp;
    }
    attn3v_mfma<<<dim3(4, 4, 32), 256, 0, stream>>>(qlb, kb, vtb, num_part, den_part);
    a3v_combine<<<2048, 256, 0, stream>>>(num_part, den_part, a3v);
    bgemm_w2t<<<dim3(4, 1, 32), 256, 0, stream>>>(zc, a3v, w2tb);
    attn1_mfma<<<dim3(64, 32), 256, 0, stream>>>(qb, klb, w2tb, outh, outhb);
    gemm_mfma<1><<<dim3(128, 4), 256, 0, stream>>>(outhb, woutb, nullptr, nullptr, nullptr, b_out, x, out);
}